// Round 5
// baseline (167.555 us; speedup 1.0000x reference)
//
#include <hip/hip_runtime.h>
#include <hip/hip_bf16.h>
#include <math.h>

#define BB 16
#define SS 2048
#define DM 384
#define DQ 64
#define M_ROWS (BB * SS)   // 32768

typedef short short8 __attribute__((ext_vector_type(8)));
typedef float f32x4  __attribute__((ext_vector_type(4)));
typedef unsigned u32x4 __attribute__((ext_vector_type(4)));

// ws layout (shorts): Wt [192][384] | Qb [B][S][64] | Kb [B][S][64] | Vt [B][64][S]
//                     | Op [2][B*S][64] f32 | Ls [2][B*S] f32
#define WT_OFF 0
#define QB_OFF 73728
#define KB_OFF (QB_OFF + M_ROWS * DQ)
#define VT_OFF (KB_OFF + M_ROWS * DQ)
#define OP_OFF (VT_OFF + BB * DQ * SS)          // 16B aligned
#define LS_OFF (OP_OFF + 2 * M_ROWS * DQ * 2)   // Op = 2*32768*64 f32

#define QSCALE 0.18033688011112042f   // 0.125 * log2(e); softmax in exp2

__device__ __forceinline__ short f2bf(float f) {
  unsigned u = __builtin_bit_cast(unsigned, f);
  unsigned r = (u + 0x7fffu + ((u >> 16) & 1u)) >> 16;
  return (short)r;
}
// packed RNE f32x2 -> bf16x2 (1 VALU op per 2 values)
__device__ __forceinline__ unsigned cvtpk(float a, float b) {
  unsigned r;
  asm("v_cvt_pk_bf16_f32 %0, %1, %2" : "=v"(r) : "v"(a), "v"(b));
  return r;
}
__device__ __forceinline__ void async16(const short* g, short* l) {
  __builtin_amdgcn_global_load_lds(
      (const __attribute__((address_space(1))) unsigned int*)g,
      (__attribute__((address_space(3))) unsigned int*)l, 16, 0, 0);
}

// ---------------------------------------------------------------------------
// Kernel 0: W [384,64] fp32 x3 -> Wt rows [mat*64+n][384] bf16.  288 x 256.
// (proven code, unchanged)
// ---------------------------------------------------------------------------
__global__ void prep_w_kernel(const float* __restrict__ Wq,
                              const float* __restrict__ Wk,
                              const float* __restrict__ Wv,
                              short* __restrict__ ws) {
  int o = blockIdx.x * 256 + threadIdx.x;        // 0 .. 73727
  int mat = o / (DM * DQ);
  int r = o % (DM * DQ);
  int k = r / DQ, n = r % DQ;                    // coalesced read
  const float* W = (mat == 0) ? Wq : (mat == 1) ? Wk : Wv;
  ws[WT_OFF + mat * (DM * DQ) + n * DM + k] = f2bf(W[k * DQ + n]);
}

// ---------------------------------------------------------------------------
// Kernel 1: QKV projection, bf16 MFMA 16x16x32.  (proven code, unchanged)
// ---------------------------------------------------------------------------
__global__ __launch_bounds__(256) void qkv_proj_mfma(
    const float* __restrict__ x, const short* __restrict__ ws_r,
    short* __restrict__ ws_w) {
  __shared__ short smem[2 * 192 * 64];   // Wtc dbuf (2 x 24 KB); Ep aliases
  short* Ep = smem;                      // 64*200 shorts, post-loop only
  const int tid = threadIdx.x;
  const int lane = tid & 63, w = tid >> 6;
  const int cidx = lane & 15, g = lane >> 4;
  const int g8 = g * 8, g4 = g * 4;
  const int sw7 = cidx & 7;
  const int rows0 = blockIdx.x * 64;
  const short* Wt = ws_r + WT_OFF;

  f32x4 acc[12];
  #pragma unroll
  for (int i = 0; i < 12; ++i) acc[i] = (f32x4){0.f, 0.f, 0.f, 0.f};

  const float* xr = x + (size_t)(rows0 + 16 * w + cidx) * DM;

  // prologue: stage k-iter 0 into buf0, preload x regs for iter 0
  #pragma unroll
  for (int it = 0; it < 6; ++it) {
    int i = it * 256 + tid;
    int row = i >> 3, gr = i & 7;
    const short* src = Wt + row * DM + ((gr ^ (row & 7)) * 8);
    async16(src, &smem[(it * 256 + w * 64) * 8]);
  }
  float4 xc0 = *(const float4*)(xr + g8);
  float4 xc1 = *(const float4*)(xr + g8 + 4);
  float4 xc2 = *(const float4*)(xr + 32 + g8);
  float4 xc3 = *(const float4*)(xr + 32 + g8 + 4);

  for (int ki = 0; ki < 6; ++ki) {
    __syncthreads();   // drains stage(ki) + this iter's x loads
    const short* cur = smem + (ki & 1) * 12288;

    if (ki < 5) {      // prefetch stage(ki+1) into the other buffer
      short* nxt = smem + ((ki + 1) & 1) * 12288;
      const int kn = (ki + 1) * 64;
      #pragma unroll
      for (int it = 0; it < 6; ++it) {
        int i = it * 256 + tid;
        int row = i >> 3, gr = i & 7;
        const short* src = Wt + row * DM + kn + ((gr ^ (row & 7)) * 8);
        async16(src, &nxt[(it * 256 + w * 64) * 8]);
      }
    }

    u32x4 ua, ub;
    ua[0] = cvtpk(xc0.x, xc0.y); ua[1] = cvtpk(xc0.z, xc0.w);
    ua[2] = cvtpk(xc1.x, xc1.y); ua[3] = cvtpk(xc1.z, xc1.w);
    ub[0] = cvtpk(xc2.x, xc2.y); ub[1] = cvtpk(xc2.z, xc2.w);
    ub[2] = cvtpk(xc3.x, xc3.y); ub[3] = cvtpk(xc3.z, xc3.w);
    short8 a0 = __builtin_bit_cast(short8, ua);
    short8 a1 = __builtin_bit_cast(short8, ub);

    if (ki < 5) {      // preload next iter's x (in flight during MFMA)
      const float* xn = xr + (ki + 1) * 64;
      xc0 = *(const float4*)(xn + g8);
      xc1 = *(const float4*)(xn + g8 + 4);
      xc2 = *(const float4*)(xn + 32 + g8);
      xc3 = *(const float4*)(xn + 32 + g8 + 4);
    }

    #pragma unroll
    for (int ct = 0; ct < 12; ++ct) {
      int row = ct * 16 + cidx;
      short8 b0 = *(const short8*)&cur[row * 64 + ((g ^ sw7) * 8)];
      short8 b1 = *(const short8*)&cur[row * 64 + (((g + 4) ^ sw7) * 8)];
      acc[ct] = __builtin_amdgcn_mfma_f32_16x16x32_bf16(a0, b0, acc[ct], 0, 0, 0);
      acc[ct] = __builtin_amdgcn_mfma_f32_16x16x32_bf16(a1, b1, acc[ct], 0, 0, 0);
    }
  }

  __syncthreads();     // all compute done; safe to clobber dbuf with Ep
  const int erow = 16 * w + g4;
  #pragma unroll
  for (int ct = 0; ct < 4; ++ct) {
    unsigned q01 = cvtpk(acc[ct][0] * QSCALE, acc[ct][1] * QSCALE);
    unsigned q23 = cvtpk(acc[ct][2] * QSCALE, acc[ct][3] * QSCALE);
    unsigned k01 = cvtpk(acc[4 + ct][0], acc[4 + ct][1]);
    unsigned k23 = cvtpk(acc[4 + ct][2], acc[4 + ct][3]);
    unsigned v01 = cvtpk(acc[8 + ct][0], acc[8 + ct][1]);
    unsigned v23 = cvtpk(acc[8 + ct][2], acc[8 + ct][3]);
    Ep[(erow + 0) * 200 + ct * 16 + cidx] = (short)q01;
    Ep[(erow + 1) * 200 + ct * 16 + cidx] = (short)(q01 >> 16);
    Ep[(erow + 2) * 200 + ct * 16 + cidx] = (short)q23;
    Ep[(erow + 3) * 200 + ct * 16 + cidx] = (short)(q23 >> 16);
    Ep[(erow + 0) * 200 + 64 + ct * 16 + cidx] = (short)k01;
    Ep[(erow + 1) * 200 + 64 + ct * 16 + cidx] = (short)(k01 >> 16);
    Ep[(erow + 2) * 200 + 64 + ct * 16 + cidx] = (short)k23;
    Ep[(erow + 3) * 200 + 64 + ct * 16 + cidx] = (short)(k23 >> 16);
    Ep[(ct * 16 + cidx) * 200 + 128 + erow + 0] = (short)v01;
    Ep[(ct * 16 + cidx) * 200 + 128 + erow + 1] = (short)(v01 >> 16);
    Ep[(ct * 16 + cidx) * 200 + 128 + erow + 2] = (short)v23;
    Ep[(ct * 16 + cidx) * 200 + 128 + erow + 3] = (short)(v23 >> 16);
  }
  __syncthreads();

  short* Qb = ws_w + QB_OFF;
  short* Kb = ws_w + KB_OFF;
  short* Vt = ws_w + VT_OFF;
  const int bidx = rows0 >> 11;
  const int srow0 = rows0 & 2047;
  #pragma unroll
  for (int t2 = 0; t2 < 2; ++t2) {
    int i = t2 * 256 + tid;            // 0..511
    int row = i >> 3, gq = i & 7;
    *(short8*)&Qb[(size_t)(rows0 + row) * DQ + gq * 8] =
        *(const short8*)&Ep[row * 200 + gq * 8];
    *(short8*)&Kb[(size_t)(rows0 + row) * DQ + gq * 8] =
        *(const short8*)&Ep[row * 200 + 64 + gq * 8];
    *(short8*)&Vt[(size_t)bidx * (64 * SS) + (size_t)row * SS + srow0 + gq * 8] =
        *(const short8*)&Ep[row * 200 + 128 + gq * 8];   // row = d here
  }
}

// ---------------------------------------------------------------------------
// Kernel 2: causal flash attention, KEY-SPLIT 2x, BARRIER-FREE.
// K/V for this XCD's 2 batches are L2-resident (1 MB of 4 MiB): LDS staging
// of L2-fit data was pure overhead (cost: a __syncthreads per superstep +
// 67.6K global_load_lds + dbuf management).  MFMA fragments now load K/V
// DIRECTLY from global (coalesced 16 B/lane; same addresses the old swizzle
// unswizzled to).  Only the wave-local Ps transpose buffer stays in LDS
// (16 KB/block).  ZERO barriers in the superstep loop: 4 waves/SIMD drift
// freely, hiding L2 latency; a block's 4 waves share K/V tiles via L1
// (16 KB/ss fits 32 KB L1).
// ---------------------------------------------------------------------------
__global__ __launch_bounds__(256, 4) void flash_mfma(
    const short* __restrict__ ws, float* __restrict__ Op,
    float* __restrict__ Ls) {
  __shared__ short Psm[4 * 1024];           // per-wave [16 q][64 k] swizzled
  const int l = blockIdx.x;                 // 0..1023
  const int b = l & 15;                     // XCD = l%8 = b%8
  const int r = l >> 4;                     // 0..63
  const int qtp = r & 31;
  const int half = r >> 5;                  // 0 or 1
  const int qt = (qtp < 16) ? qtp : 47 - qtp;   // causal balance pairing
  const int q0 = qt * 64;
  const int hsplit = ((qt + 2) >> 1) * 64;  // ceil((qt+1)/2)*64
  const int kstart = half ? hsplit : 0;
  const int kend = half ? (qt + 1) * 64 : hsplit;
  const int nss = (kend - kstart) >> 6;     // 64-key supersteps

  const int tid = threadIdx.x;
  const int lane = tid & 63, w = tid >> 6;
  const int cidx = lane & 15, g = lane >> 4;
  const int g8 = g * 8, g4 = g * 4;
  const int sw7 = cidx & 7;
  short* Ps = Psm + w * 1024;

  const short* Qb = ws + QB_OFF + (size_t)b * SS * DQ;
  const short* Kb = ws + KB_OFF + (size_t)b * SS * DQ;
  const short* Vt = ws + VT_OFF + (size_t)b * 64 * SS;

  const int qrow = q0 + w * 16;             // wave w owns queries qrow..qrow+15
  const int qglob = qrow + cidx;            // this lane's query
  short8 qf0 = *(const short8*)&Qb[(size_t)qglob * DQ + g8];
  short8 qf1 = *(const short8*)&Qb[(size_t)qglob * DQ + 32 + g8];

  f32x4 o[4];
  #pragma unroll
  for (int i = 0; i < 4; ++i) o[i] = (f32x4){0.f, 0.f, 0.f, 0.f};
  float lsum = 0.f;

  // per-lane K/V base addresses (row picked by cidx, granule by g)
  const short* kp = Kb + (size_t)(kstart + cidx) * DQ + g8;   // + ct*16*DQ rows
  const short* vp = Vt + (size_t)cidx * SS + kstart + g8;     // + dt*16*SS rows

  for (int ssi = 0; ssi < nss; ++ssi) {
    const int kbase = kstart + ssi * 64;
    const short* kc = kp + (size_t)ssi * 64 * DQ;

    // S^T = K Q^T : 4 key-tiles of 16, K straight from L1/L2
    f32x4 sc[4];
    __builtin_amdgcn_s_setprio(1);
    #pragma unroll
    for (int ct = 0; ct < 4; ++ct) {
      short8 kf0 = *(const short8*)&kc[(size_t)ct * 16 * DQ];
      short8 kf1 = *(const short8*)&kc[(size_t)ct * 16 * DQ + 32];
      f32x4 a = (f32x4){0.f, 0.f, 0.f, 0.f};
      a = __builtin_amdgcn_mfma_f32_16x16x32_bf16(kf0, qf0, a, 0, 0, 0);
      a = __builtin_amdgcn_mfma_f32_16x16x32_bf16(kf1, qf1, a, 0, 0, 0);
      sc[ct] = a;
    }
    __builtin_amdgcn_s_setprio(0);
    if (ssi == nss - 1) {                   // diagonal tile: mask key > q
      #pragma unroll
      for (int ct = 0; ct < 4; ++ct) {
        int key = kbase + ct * 16 + g4;
        #pragma unroll
        for (int rr = 0; rr < 4; ++rr)
          if (key + rr > qglob) sc[ct][rr] = -1e30f;
      }
    }
    // static-max softmax: p = 2^s, per-lane lsum, no rescale
    #pragma unroll
    for (int ct = 0; ct < 4; ++ct) {
      #pragma unroll
      for (int rr = 0; rr < 4; ++rr) {
        float p = __builtin_amdgcn_exp2f(sc[ct][rr]);
        sc[ct][rr] = p;
        lsum += p;
      }
      // P^T -> Ps[q][key] (wave-local, swizzled), one b64 write per ct
      int gb = ct * 2 + (g >> 1);
      uint2 pk;
      pk.x = cvtpk(sc[ct][0], sc[ct][1]);
      pk.y = cvtpk(sc[ct][2], sc[ct][3]);
      *(uint2*)&Ps[cidx * 64 + ((gb ^ sw7) * 8) + (g & 1) * 4] = pk;
    }
    // O^T += V^T P^T  (K=64 keys -> 2 x K32 per d-tile), V straight from L1/L2
    __builtin_amdgcn_s_setprio(1);
    #pragma unroll
    for (int ks = 0; ks < 2; ++ks) {
      short8 pf = *(const short8*)&Ps[cidx * 64 + (((ks * 4 + g) ^ sw7) * 8)];
      const short* vc = vp + (size_t)ssi * 64 + ks * 32;
      #pragma unroll
      for (int dt = 0; dt < 4; ++dt) {
        short8 vf = *(const short8*)&vc[(size_t)dt * 16 * SS];
        o[dt] = __builtin_amdgcn_mfma_f32_16x16x32_bf16(vf, pf, o[dt], 0, 0, 0);
      }
    }
    __builtin_amdgcn_s_setprio(0);
  }

  // query qglob's partial lsum sits in lanes {cidx, cidx+16, cidx+32, cidx+48}
  lsum += __shfl_xor(lsum, 16);
  lsum += __shfl_xor(lsum, 32);

  // unnormalized partial store; lane holds d = dt*16 + g4 + r for query qglob
  float* op = Op + (size_t)half * (M_ROWS * DQ) + ((size_t)b * SS + qglob) * DQ;
  #pragma unroll
  for (int dt = 0; dt < 4; ++dt) {
    float4 v = make_float4(o[dt][0], o[dt][1], o[dt][2], o[dt][3]);
    *(float4*)&op[dt * 16 + g4] = v;
  }
  if (g == 0)          // lanes 0..15 cover this wave's 16 queries
    Ls[(size_t)half * M_ROWS + (size_t)b * SS + qglob] = lsum;
}

// ---------------------------------------------------------------------------
// Kernel 3: combine halves + normalize.  O = (O0+O1) / (l0+l1).
// (proven code, unchanged)
// ---------------------------------------------------------------------------
__global__ __launch_bounds__(256) void norm_kernel(
    const float* __restrict__ Op, const float* __restrict__ Ls,
    float* __restrict__ O) {
  int idx = blockIdx.x * 256 + threadIdx.x;   // 0..524287
  int row = idx >> 4, q4 = idx & 15;
  float li = 1.0f / (Ls[row] + Ls[M_ROWS + row]);
  float4 a = *(const float4*)&Op[(size_t)row * DQ + q4 * 4];
  float4 c = *(const float4*)&Op[(size_t)(M_ROWS + row) * DQ + q4 * 4];
  float4 v = make_float4((a.x + c.x) * li, (a.y + c.y) * li,
                         (a.z + c.z) * li, (a.w + c.w) * li);
  *(float4*)&O[(size_t)row * DQ + q4 * 4] = v;
}

extern "C" void kernel_launch(void* const* d_in, const int* in_sizes, int n_in,
                              void* d_out, int out_size, void* d_ws, size_t ws_size,
                              hipStream_t stream) {
  const float* x  = (const float*)d_in[0];
  const float* Wq = (const float*)d_in[1];
  const float* Wk = (const float*)d_in[2];
  const float* Wv = (const float*)d_in[3];
  short* ws = (short*)d_ws;          // ~29.8 MB bf16/f32 scratch
  float* out = (float*)d_out;
  float* Op = (float*)(ws + OP_OFF);
  float* Ls = (float*)(ws + LS_OFF);

  prep_w_kernel<<<288, 256, 0, stream>>>(Wq, Wk, Wv, ws);
  qkv_proj_mfma<<<M_ROWS / 64, 256, 0, stream>>>(x, ws, ws);
  flash_mfma<<<1024, 256, 0, stream>>>(ws, Op, Ls);
  norm_kernel<<<2048, 256, 0, stream>>>(Op, Ls, out);
}

// Round 6
// 130.297 us; speedup vs baseline: 1.2859x; 1.2859x over previous
//
#include <hip/hip_runtime.h>
#include <hip/hip_bf16.h>
#include <math.h>

#define BB 16
#define SS 2048
#define DM 384
#define DQ 64
#define M_ROWS (BB * SS)   // 32768

typedef short short8 __attribute__((ext_vector_type(8)));
typedef float f32x4  __attribute__((ext_vector_type(4)));
typedef unsigned u32x4 __attribute__((ext_vector_type(4)));

// ws layout (shorts): Wt [192][384] | Qb [B][S][64] | Kb [B][S][64] | Vt [B][64][S]
//                     | Op [2][B*S][64] f32 | Ls [2][B*S] f32
#define WT_OFF 0
#define QB_OFF 73728
#define KB_OFF (QB_OFF + M_ROWS * DQ)
#define VT_OFF (KB_OFF + M_ROWS * DQ)
#define OP_OFF (VT_OFF + BB * DQ * SS)          // 16B aligned
#define LS_OFF (OP_OFF + 2 * M_ROWS * DQ * 2)   // Op = 2*32768*64 f32

#define QSCALE 0.18033688011112042f   // 0.125 * log2(e); softmax in exp2

__device__ __forceinline__ short f2bf(float f) {
  unsigned u = __builtin_bit_cast(unsigned, f);
  unsigned r = (u + 0x7fffu + ((u >> 16) & 1u)) >> 16;
  return (short)r;
}
// packed RNE f32x2 -> bf16x2 (1 VALU op per 2 values)
__device__ __forceinline__ unsigned cvtpk(float a, float b) {
  unsigned r;
  asm("v_cvt_pk_bf16_f32 %0, %1, %2" : "=v"(r) : "v"(a), "v"(b));
  return r;
}
__device__ __forceinline__ void async16(const short* g, short* l) {
  __builtin_amdgcn_global_load_lds(
      (const __attribute__((address_space(1))) unsigned int*)g,
      (__attribute__((address_space(3))) unsigned int*)l, 16, 0, 0);
}

// ---------------------------------------------------------------------------
// Kernel 0: W [384,64] fp32 x3 -> Wt rows [mat*64+n][384] bf16.  288 x 256.
// (proven code, unchanged)
// ---------------------------------------------------------------------------
__global__ void prep_w_kernel(const float* __restrict__ Wq,
                              const float* __restrict__ Wk,
                              const float* __restrict__ Wv,
                              short* __restrict__ ws) {
  int o = blockIdx.x * 256 + threadIdx.x;        // 0 .. 73727
  int mat = o / (DM * DQ);
  int r = o % (DM * DQ);
  int k = r / DQ, n = r % DQ;                    // coalesced read
  const float* W = (mat == 0) ? Wq : (mat == 1) ? Wk : Wv;
  ws[WT_OFF + mat * (DM * DQ) + n * DM + k] = f2bf(W[k * DQ + n]);
}

// ---------------------------------------------------------------------------
// Kernel 1 (v2): QKV projection, PER-MATRIX blocks, zero in-loop barriers.
// Block l: xcd = l&7, idx = l>>3, mat = idx%3, rtl = idx/3;
//          row_tile r = rtl*8 + xcd  (the 3 mats of a row-tile share an XCD
//          so 2nd/3rd x reads are L2 hits).
// Each block: stage ONE matrix's Wt slice [64 n][384 k] bf16 = 48 KB into
// LDS ONCE (granule-XOR swizzle, same conflict math as before: row stride
// 768 B == 0 mod 128 B), one syncthreads, then 6 pure
// {x-load -> cvt -> 8 MFMA} iterations with NO barriers -- fully
// software-pipelineable.  3 blocks/CU (12 waves/CU, was 8).  Epilogue
// writes registers straight to Qb/Kb/Vt (no Ep LDS transpose).
// ---------------------------------------------------------------------------
__global__ __launch_bounds__(256, 3) void qkv_proj_v2(
    const float* __restrict__ x, const short* __restrict__ ws_r,
    short* __restrict__ ws_w) {
  __shared__ short Ws[64 * 384];         // 48 KB, one matrix slice
  const int tid = threadIdx.x;
  const int lane = tid & 63, w = tid >> 6;
  const int cidx = lane & 15, g = lane >> 4;
  const int g8 = g * 8, g4 = g * 4;
  const int sw7 = cidx & 7;

  const int l = blockIdx.x;              // 0..1535
  const int xcd = l & 7;
  const int idx = l >> 3;                // 0..191
  const int mat = idx % 3;
  const int rtl = idx / 3;               // 0..63
  const int rt = rtl * 8 + xcd;          // row tile 0..511
  const int rows0 = rt * 64;

  const short* Wtg = ws_r + WT_OFF + mat * (DM * DQ);

  // ---- stage whole Wt slice: 64 rows x 48 granules of 8 shorts ----
  // dest granule i is linear (wave-uniform base + lane*16); source granule
  // pre-swizzled: within each 8-granule window, gr ^ (n&7).
  #pragma unroll
  for (int it = 0; it < 12; ++it) {
    int i = it * 256 + tid;              // 0..3071
    int n = i / 48, gr = i % 48;
    const short* src = Wtg + n * DM + (gr >> 3) * 64 + (((gr & 7) ^ (n & 7)) * 8);
    async16(src, &Ws[i * 8]);
  }

  const float* xr = x + (size_t)(rows0 + 16 * w + cidx) * DM;
  // preload iter-0 x while the stage is in flight
  float4 xc0 = *(const float4*)(xr + g8);
  float4 xc1 = *(const float4*)(xr + g8 + 4);
  float4 xc2 = *(const float4*)(xr + 32 + g8);
  float4 xc3 = *(const float4*)(xr + 32 + g8 + 4);

  f32x4 acc[4];
  #pragma unroll
  for (int i = 0; i < 4; ++i) acc[i] = (f32x4){0.f, 0.f, 0.f, 0.f};

  __syncthreads();     // drains stage (and iter-0 x loads); the ONLY barrier

  for (int ki = 0; ki < 6; ++ki) {
    u32x4 ua, ub;
    ua[0] = cvtpk(xc0.x, xc0.y); ua[1] = cvtpk(xc0.z, xc0.w);
    ua[2] = cvtpk(xc1.x, xc1.y); ua[3] = cvtpk(xc1.z, xc1.w);
    ub[0] = cvtpk(xc2.x, xc2.y); ub[1] = cvtpk(xc2.z, xc2.w);
    ub[2] = cvtpk(xc3.x, xc3.y); ub[3] = cvtpk(xc3.z, xc3.w);
    short8 a0 = __builtin_bit_cast(short8, ua);
    short8 a1 = __builtin_bit_cast(short8, ub);

    if (ki < 5) {      // prefetch next iter's x (in flight during MFMA)
      const float* xn = xr + (ki + 1) * 64;
      xc0 = *(const float4*)(xn + g8);
      xc1 = *(const float4*)(xn + g8 + 4);
      xc2 = *(const float4*)(xn + 32 + g8);
      xc3 = *(const float4*)(xn + 32 + g8 + 4);
    }

    #pragma unroll
    for (int ct = 0; ct < 4; ++ct) {
      int row = ct * 16 + cidx;          // row&7 == sw7
      const short* wrow = &Ws[row * 384 + ki * 64];
      short8 b0 = *(const short8*)&wrow[(g ^ sw7) * 8];
      short8 b1 = *(const short8*)&wrow[((g + 4) ^ sw7) * 8];
      acc[ct] = __builtin_amdgcn_mfma_f32_16x16x32_bf16(a0, b0, acc[ct], 0, 0, 0);
      acc[ct] = __builtin_amdgcn_mfma_f32_16x16x32_bf16(a1, b1, acc[ct], 0, 0, 0);
    }
  }

  // ---- epilogue: registers -> global, no LDS round trip ----
  // D layout: m (x-row within 16) = g4 + rr, n = ct*16 + cidx.
  const int erow = 16 * w + g4;          // + rr = block-local m
  if (mat == 2) {
    // V: Vt[batch][d = n][s = rows0local + m], pack rr 0..3 -> 8 B store
    short* Vt = ws_w + VT_OFF;
    const int bidx = rows0 >> 11;
    const int srow0 = rows0 & 2047;
    #pragma unroll
    for (int ct = 0; ct < 4; ++ct) {
      uint2 pk;
      pk.x = cvtpk(acc[ct][0], acc[ct][1]);
      pk.y = cvtpk(acc[ct][2], acc[ct][3]);
      *(uint2*)&Vt[(size_t)bidx * (64 * SS) + (size_t)(ct * 16 + cidx) * SS +
                   srow0 + erow] = pk;
    }
  } else {
    // Q (scaled) / K: [rows0+m][n], 2-B scalar stores (16 lanes = 32 B runs)
    short* Ob = ws_w + (mat == 0 ? QB_OFF : KB_OFF);
    const float sc = (mat == 0) ? QSCALE : 1.0f;
    #pragma unroll
    for (int ct = 0; ct < 4; ++ct)
      #pragma unroll
      for (int rr = 0; rr < 4; ++rr)
        Ob[(size_t)(rows0 + erow + rr) * DQ + ct * 16 + cidx] =
            f2bf(acc[ct][rr] * sc);
  }
}

// ---------------------------------------------------------------------------
// Kernel 2: causal flash attention, KEY-SPLIT 2x, LDS-staged (proven R4 code,
// reverted from the barrier-free experiment: direct-global K/V exposed L2
// latency -- MfmaUtil 4.9%, 65.7 us.  Staged version measured ~22 us).
// ---------------------------------------------------------------------------
__global__ __launch_bounds__(256, 4) void flash_mfma(
    const short* __restrict__ ws, float* __restrict__ Op,
    float* __restrict__ Ls) {
  __shared__ short smem[20480];   // KsA 0 | KsB 4096 | VtsA 8192 | VtsB 12288 | Ps 16384
  const int l = blockIdx.x;                 // 0..1023
  const int b = l & 15;
  const int r = l >> 4;                     // 0..63
  const int qtp = r & 31;
  const int half = r >> 5;                  // 0 or 1
  const int qt = (qtp < 16) ? qtp : 47 - qtp;   // causal balance pairing
  const int q0 = qt * 64;
  const int hsplit = ((qt + 2) >> 1) * 64;  // ceil((qt+1)/2)*64
  const int kstart = half ? hsplit : 0;
  const int kend = half ? (qt + 1) * 64 : hsplit;
  const int nss = (kend - kstart) >> 6;     // 64-key supersteps

  const int tid = threadIdx.x;
  const int lane = tid & 63, w = tid >> 6;
  const int cidx = lane & 15, g = lane >> 4;
  const int g8 = g * 8, g4 = g * 4;
  const int sw7 = cidx & 7;
  short* Ps = smem + 16384 + w * 1024;      // [16 q][64 k] swizzled, per wave

  const short* Qb = ws + QB_OFF + (size_t)b * SS * DQ;
  const short* Kb = ws + KB_OFF + (size_t)b * SS * DQ;
  const short* Vt = ws + VT_OFF + (size_t)b * 64 * SS;

  const int qrow = q0 + w * 16;             // wave w owns queries qrow..qrow+15
  const int qglob = qrow + cidx;            // this lane's query
  short8 qf0 = *(const short8*)&Qb[(size_t)qglob * DQ + g8];
  short8 qf1 = *(const short8*)&Qb[(size_t)qglob * DQ + 32 + g8];

  // staging: round r covers rows r*32..r*32+31; (row+32)&7 == row&7
  const int srow = tid >> 3, sgr = tid & 7;
  const int ssw = (sgr ^ (srow & 7)) * 8;
  const short* kb0 = Kb + (size_t)(kstart + srow) * DQ + ssw;
  const short* kb1 = Kb + (size_t)(kstart + srow + 32) * DQ + ssw;
  const short* vb0 = Vt + (size_t)srow * SS + kstart + ssw;
  const short* vb1 = Vt + (size_t)(srow + 32) * SS + kstart + ssw;
  const int dst0 = (w * 64) * 8, dst1 = (256 + w * 64) * 8;

  f32x4 o[4];
  #pragma unroll
  for (int i = 0; i < 4; ++i) o[i] = (f32x4){0.f, 0.f, 0.f, 0.f};
  float lsum = 0.f;

  if (nss > 0) {
    // preamble: local superstep 0 -> buffer 0
    async16(kb0, &smem[dst0]);
    async16(kb1, &smem[dst1]);
    async16(vb0, &smem[8192 + dst0]);
    async16(vb1, &smem[8192 + dst1]);

    for (int ssi = 0; ssi < nss; ++ssi) {
      __syncthreads();   // drains prefetch of ss `ssi` (issued last iteration)

      {   // prefetch ss+1 into the other buffer (clamped: always in-bounds)
        int nb = (ssi + 1) * 64;
        if (nb >= kend - kstart) nb = 0;    // dead prefetch, valid addr
        const int nbuf = ((ssi + 1) & 1) * 4096;
        const size_t koff = (size_t)nb * DQ;
        async16(kb0 + koff, &smem[nbuf + dst0]);
        async16(kb1 + koff, &smem[nbuf + dst1]);
        async16(vb0 + nb, &smem[8192 + nbuf + dst0]);
        async16(vb1 + nb, &smem[8192 + nbuf + dst1]);
      }

      const short* Kc = smem + (ssi & 1) * 4096;
      const short* Vc = smem + 8192 + (ssi & 1) * 4096;
      const int kbase = kstart + ssi * 64;

      // S^T = K Q^T : 4 key-tiles of 16
      f32x4 sc[4];
      __builtin_amdgcn_s_setprio(1);
      #pragma unroll
      for (int ct = 0; ct < 4; ++ct) {
        int krow = ct * 16 + cidx;          // krow&7 == sw7
        short8 kf0 = *(const short8*)&Kc[krow * 64 + ((g ^ sw7) * 8)];
        short8 kf1 = *(const short8*)&Kc[krow * 64 + (((g + 4) ^ sw7) * 8)];
        f32x4 a = (f32x4){0.f, 0.f, 0.f, 0.f};
        a = __builtin_amdgcn_mfma_f32_16x16x32_bf16(kf0, qf0, a, 0, 0, 0);
        a = __builtin_amdgcn_mfma_f32_16x16x32_bf16(kf1, qf1, a, 0, 0, 0);
        sc[ct] = a;
      }
      __builtin_amdgcn_s_setprio(0);
      if (ssi == nss - 1) {                 // diagonal tile: mask key > q
        #pragma unroll
        for (int ct = 0; ct < 4; ++ct) {
          int key = kbase + ct * 16 + g4;
          #pragma unroll
          for (int rr = 0; rr < 4; ++rr)
            if (key + rr > qglob) sc[ct][rr] = -1e30f;
        }
      }
      // static-max softmax: p = 2^s, per-lane lsum, no rescale
      #pragma unroll
      for (int ct = 0; ct < 4; ++ct) {
        #pragma unroll
        for (int rr = 0; rr < 4; ++rr) {
          float p = __builtin_amdgcn_exp2f(sc[ct][rr]);
          sc[ct][rr] = p;
          lsum += p;
        }
        // P^T -> Ps[q][key] (wave-local, swizzled), one b64 write per ct
        int gb = ct * 2 + (g >> 1);
        uint2 pk;
        pk.x = cvtpk(sc[ct][0], sc[ct][1]);
        pk.y = cvtpk(sc[ct][2], sc[ct][3]);
        *(uint2*)&Ps[cidx * 64 + ((gb ^ sw7) * 8) + (g & 1) * 4] = pk;
      }
      // O^T += V^T P^T  (K=64 keys -> 2 x K32 per d-tile)
      __builtin_amdgcn_s_setprio(1);
      #pragma unroll
      for (int ks = 0; ks < 2; ++ks) {
        short8 pf = *(const short8*)&Ps[cidx * 64 + (((ks * 4 + g) ^ sw7) * 8)];
        #pragma unroll
        for (int dt = 0; dt < 4; ++dt) {
          int vrow = dt * 16 + cidx;        // vrow&7 == sw7
          short8 vf = *(const short8*)&Vc[vrow * 64 + (((ks * 4 + g) ^ sw7) * 8)];
          o[dt] = __builtin_amdgcn_mfma_f32_16x16x32_bf16(vf, pf, o[dt], 0, 0, 0);
        }
      }
      __builtin_amdgcn_s_setprio(0);
    }
  }

  // query qglob's partial lsum sits in lanes {cidx, cidx+16, cidx+32, cidx+48}
  lsum += __shfl_xor(lsum, 16);
  lsum += __shfl_xor(lsum, 32);

  // unnormalized partial store; lane holds d = dt*16 + g4 + r for query qglob
  float* op = Op + (size_t)half * (M_ROWS * DQ) + ((size_t)b * SS + qglob) * DQ;
  #pragma unroll
  for (int dt = 0; dt < 4; ++dt) {
    float4 v = make_float4(o[dt][0], o[dt][1], o[dt][2], o[dt][3]);
    *(float4*)&op[dt * 16 + g4] = v;
  }
  if (g == 0)          // lanes 0..15 cover this wave's 16 queries
    Ls[(size_t)half * M_ROWS + (size_t)b * SS + qglob] = lsum;
}

// ---------------------------------------------------------------------------
// Kernel 3: combine halves + normalize.  O = (O0+O1) / (l0+l1).
// (proven code, unchanged)
// ---------------------------------------------------------------------------
__global__ __launch_bounds__(256) void norm_kernel(
    const float* __restrict__ Op, const float* __restrict__ Ls,
    float* __restrict__ O) {
  int idx = blockIdx.x * 256 + threadIdx.x;   // 0..524287
  int row = idx >> 4, q4 = idx & 15;
  float li = 1.0f / (Ls[row] + Ls[M_ROWS + row]);
  float4 a = *(const float4*)&Op[(size_t)row * DQ + q4 * 4];
  float4 c = *(const float4*)&Op[(size_t)(M_ROWS + row) * DQ + q4 * 4];
  float4 v = make_float4((a.x + c.x) * li, (a.y + c.y) * li,
                         (a.z + c.z) * li, (a.w + c.w) * li);
  *(float4*)&O[(size_t)row * DQ + q4 * 4] = v;
}

extern "C" void kernel_launch(void* const* d_in, const int* in_sizes, int n_in,
                              void* d_out, int out_size, void* d_ws, size_t ws_size,
                              hipStream_t stream) {
  const float* x  = (const float*)d_in[0];
  const float* Wq = (const float*)d_in[1];
  const float* Wk = (const float*)d_in[2];
  const float* Wv = (const float*)d_in[3];
  short* ws = (short*)d_ws;          // ~29.8 MB bf16/f32 scratch
  float* out = (float*)d_out;
  float* Op = (float*)(ws + OP_OFF);
  float* Ls = (float*)(ws + LS_OFF);

  prep_w_kernel<<<288, 256, 0, stream>>>(Wq, Wk, Wv, ws);
  qkv_proj_v2<<<1536, 256, 0, stream>>>(x, ws, ws);
  flash_mfma<<<1024, 256, 0, stream>>>(ws, Op, Ls);
  norm_kernel<<<2048, 256, 0, stream>>>(Op, Ls, out);
}

// Round 7
// 128.485 us; speedup vs baseline: 1.3041x; 1.0141x over previous
//
#include <hip/hip_runtime.h>
#include <hip/hip_bf16.h>
#include <math.h>

#define BB 16
#define SS 2048
#define DM 384
#define DQ 64
#define M_ROWS (BB * SS)   // 32768

typedef short short8 __attribute__((ext_vector_type(8)));
typedef float f32x4  __attribute__((ext_vector_type(4)));
typedef unsigned u32x4 __attribute__((ext_vector_type(4)));

// ws layout (shorts): Wt [192][384] | Qb [B][S][64] | Kb [B][S][64] | Vt [B][64][S]
//                     | Op [2][B*S][64] f32 | Ls [2][B*S] f32
#define WT_OFF 0
#define QB_OFF 73728
#define KB_OFF (QB_OFF + M_ROWS * DQ)
#define VT_OFF (KB_OFF + M_ROWS * DQ)
#define OP_OFF (VT_OFF + BB * DQ * SS)          // 16B aligned
#define LS_OFF (OP_OFF + 2 * M_ROWS * DQ * 2)   // Op = 2*32768*64 f32

#define QSCALE 0.18033688011112042f   // 0.125 * log2(e); softmax in exp2

__device__ __forceinline__ short f2bf(float f) {
  unsigned u = __builtin_bit_cast(unsigned, f);
  unsigned r = (u + 0x7fffu + ((u >> 16) & 1u)) >> 16;
  return (short)r;
}
// packed RNE f32x2 -> bf16x2 (1 VALU op per 2 values)
__device__ __forceinline__ unsigned cvtpk(float a, float b) {
  unsigned r;
  asm("v_cvt_pk_bf16_f32 %0, %1, %2" : "=v"(r) : "v"(a), "v"(b));
  return r;
}
__device__ __forceinline__ void async16(const short* g, short* l) {
  __builtin_amdgcn_global_load_lds(
      (const __attribute__((address_space(1))) unsigned int*)g,
      (__attribute__((address_space(3))) unsigned int*)l, 16, 0, 0);
}

// ---------------------------------------------------------------------------
// Kernel 0: W [384,64] fp32 x3 -> Wt rows [mat*64+n][384] bf16.  288 x 256.
// (proven code, unchanged)
// ---------------------------------------------------------------------------
__global__ void prep_w_kernel(const float* __restrict__ Wq,
                              const float* __restrict__ Wk,
                              const float* __restrict__ Wv,
                              short* __restrict__ ws) {
  int o = blockIdx.x * 256 + threadIdx.x;        // 0 .. 73727
  int mat = o / (DM * DQ);
  int r = o % (DM * DQ);
  int k = r / DQ, n = r % DQ;                    // coalesced read
  const float* W = (mat == 0) ? Wq : (mat == 1) ? Wk : Wv;
  ws[WT_OFF + mat * (DM * DQ) + n * DM + k] = f2bf(W[k * DQ + n]);
}

// ---------------------------------------------------------------------------
// Kernel 1 (v3): QKV projection, 8-WAVE blocks (512 thr), ct-split.
// Same math/swizzle/traffic as the proven v1 (64 rows x 192 cols, dbuf Wtc
// staging, one barrier per K-iter, Ep transpose epilogue), but wave-pairs
// share a 16-row group and split the 12 col-tiles 6/6:
//   acc/wave 48->24 VGPR, stage issue 6->3 gload_lds per thread,
//   occupancy 3 waves/SIMD -> 4-6 waves/SIMD (latency hiding for the
//   barrier-coupled 24 KB stage drains, the presumed qkv bottleneck).
// x still read exactly once.
// ---------------------------------------------------------------------------
__global__ __launch_bounds__(512, 4) void qkv_proj_v3(
    const float* __restrict__ x, const short* __restrict__ ws_r,
    short* __restrict__ ws_w) {
  __shared__ short smem[2 * 192 * 64];   // Wtc dbuf (2 x 24 KB); Ep aliases
  short* Ep = smem;                      // 64*200 shorts, post-loop only
  const int tid = threadIdx.x;           // 0..511
  const int lane = tid & 63, w = tid >> 6;   // w 0..7
  const int wg = w >> 1;                 // wave-group 0..3 (16-row group)
  const int ctbase = (w & 1) * 6;        // ct half: 0..5 or 6..11
  const int cidx = lane & 15, g = lane >> 4;
  const int g8 = g * 8, g4 = g * 4;
  const int sw7 = cidx & 7;
  const int rows0 = blockIdx.x * 64;
  const short* Wt = ws_r + WT_OFF;

  f32x4 acc[6];
  #pragma unroll
  for (int i = 0; i < 6; ++i) acc[i] = (f32x4){0.f, 0.f, 0.f, 0.f};

  const float* xr = x + (size_t)(rows0 + 16 * wg + cidx) * DM;

  // prologue: stage k-iter 0 into buf0 (1536 granules, 3 per thread)
  #pragma unroll
  for (int it = 0; it < 3; ++it) {
    int i = it * 512 + tid;
    int row = i >> 3, gr = i & 7;
    const short* src = Wt + row * DM + ((gr ^ (row & 7)) * 8);
    async16(src, &smem[(it * 512 + w * 64) * 8]);
  }
  float4 xc0 = *(const float4*)(xr + g8);
  float4 xc1 = *(const float4*)(xr + g8 + 4);
  float4 xc2 = *(const float4*)(xr + 32 + g8);
  float4 xc3 = *(const float4*)(xr + 32 + g8 + 4);

  for (int ki = 0; ki < 6; ++ki) {
    __syncthreads();   // drains stage(ki) + this iter's x loads
    const short* cur = smem + (ki & 1) * 12288;

    if (ki < 5) {      // prefetch stage(ki+1) into the other buffer
      short* nxt = smem + ((ki + 1) & 1) * 12288;
      const int kn = (ki + 1) * 64;
      #pragma unroll
      for (int it = 0; it < 3; ++it) {
        int i = it * 512 + tid;
        int row = i >> 3, gr = i & 7;
        const short* src = Wt + row * DM + kn + ((gr ^ (row & 7)) * 8);
        async16(src, &nxt[(it * 512 + w * 64) * 8]);
      }
    }

    u32x4 ua, ub;
    ua[0] = cvtpk(xc0.x, xc0.y); ua[1] = cvtpk(xc0.z, xc0.w);
    ua[2] = cvtpk(xc1.x, xc1.y); ua[3] = cvtpk(xc1.z, xc1.w);
    ub[0] = cvtpk(xc2.x, xc2.y); ub[1] = cvtpk(xc2.z, xc2.w);
    ub[2] = cvtpk(xc3.x, xc3.y); ub[3] = cvtpk(xc3.z, xc3.w);
    short8 a0 = __builtin_bit_cast(short8, ua);
    short8 a1 = __builtin_bit_cast(short8, ub);

    if (ki < 5) {      // preload next iter's x (in flight during MFMA)
      const float* xn = xr + (ki + 1) * 64;
      xc0 = *(const float4*)(xn + g8);
      xc1 = *(const float4*)(xn + g8 + 4);
      xc2 = *(const float4*)(xn + 32 + g8);
      xc3 = *(const float4*)(xn + 32 + g8 + 4);
    }

    #pragma unroll
    for (int j = 0; j < 6; ++j) {
      int row = (ctbase + j) * 16 + cidx;
      short8 b0 = *(const short8*)&cur[row * 64 + ((g ^ sw7) * 8)];
      short8 b1 = *(const short8*)&cur[row * 64 + (((g + 4) ^ sw7) * 8)];
      acc[j] = __builtin_amdgcn_mfma_f32_16x16x32_bf16(a0, b0, acc[j], 0, 0, 0);
      acc[j] = __builtin_amdgcn_mfma_f32_16x16x32_bf16(a1, b1, acc[j], 0, 0, 0);
    }
  }

  __syncthreads();     // all compute done; safe to clobber dbuf with Ep
  const int erow = 16 * wg + g4;
  #pragma unroll
  for (int j = 0; j < 6; ++j) {
    const int ct = ctbase + j;
    if (ct < 4) {            // Q, scaled
      unsigned p01 = cvtpk(acc[j][0] * QSCALE, acc[j][1] * QSCALE);
      unsigned p23 = cvtpk(acc[j][2] * QSCALE, acc[j][3] * QSCALE);
      Ep[(erow + 0) * 200 + ct * 16 + cidx] = (short)p01;
      Ep[(erow + 1) * 200 + ct * 16 + cidx] = (short)(p01 >> 16);
      Ep[(erow + 2) * 200 + ct * 16 + cidx] = (short)p23;
      Ep[(erow + 3) * 200 + ct * 16 + cidx] = (short)(p23 >> 16);
    } else if (ct < 8) {     // K
      unsigned p01 = cvtpk(acc[j][0], acc[j][1]);
      unsigned p23 = cvtpk(acc[j][2], acc[j][3]);
      Ep[(erow + 0) * 200 + 64 + (ct - 4) * 16 + cidx] = (short)p01;
      Ep[(erow + 1) * 200 + 64 + (ct - 4) * 16 + cidx] = (short)(p01 >> 16);
      Ep[(erow + 2) * 200 + 64 + (ct - 4) * 16 + cidx] = (short)p23;
      Ep[(erow + 3) * 200 + 64 + (ct - 4) * 16 + cidx] = (short)(p23 >> 16);
    } else {                 // V, transposed
      unsigned p01 = cvtpk(acc[j][0], acc[j][1]);
      unsigned p23 = cvtpk(acc[j][2], acc[j][3]);
      Ep[((ct - 8) * 16 + cidx) * 200 + 128 + erow + 0] = (short)p01;
      Ep[((ct - 8) * 16 + cidx) * 200 + 128 + erow + 1] = (short)(p01 >> 16);
      Ep[((ct - 8) * 16 + cidx) * 200 + 128 + erow + 2] = (short)p23;
      Ep[((ct - 8) * 16 + cidx) * 200 + 128 + erow + 3] = (short)(p23 >> 16);
    }
  }
  __syncthreads();

  short* Qb = ws_w + QB_OFF;
  short* Kb = ws_w + KB_OFF;
  short* Vt = ws_w + VT_OFF;
  const int bidx = rows0 >> 11;
  const int srow0 = rows0 & 2047;
  {
    int i = tid;                       // 0..511
    int row = i >> 3, gq = i & 7;
    *(short8*)&Qb[(size_t)(rows0 + row) * DQ + gq * 8] =
        *(const short8*)&Ep[row * 200 + gq * 8];
    *(short8*)&Kb[(size_t)(rows0 + row) * DQ + gq * 8] =
        *(const short8*)&Ep[row * 200 + 64 + gq * 8];
    *(short8*)&Vt[(size_t)bidx * (64 * SS) + (size_t)row * SS + srow0 + gq * 8] =
        *(const short8*)&Ep[row * 200 + 128 + gq * 8];   // row = d here
  }
}

// ---------------------------------------------------------------------------
// Kernel 2: causal flash attention, KEY-SPLIT 2x, LDS-staged.
// (proven R4 code, unchanged)
// ---------------------------------------------------------------------------
__global__ __launch_bounds__(256, 4) void flash_mfma(
    const short* __restrict__ ws, float* __restrict__ Op,
    float* __restrict__ Ls) {
  __shared__ short smem[20480];   // KsA 0 | KsB 4096 | VtsA 8192 | VtsB 12288 | Ps 16384
  const int l = blockIdx.x;                 // 0..1023
  const int b = l & 15;
  const int r = l >> 4;                     // 0..63
  const int qtp = r & 31;
  const int half = r >> 5;                  // 0 or 1
  const int qt = (qtp < 16) ? qtp : 47 - qtp;   // causal balance pairing
  const int q0 = qt * 64;
  const int hsplit = ((qt + 2) >> 1) * 64;  // ceil((qt+1)/2)*64
  const int kstart = half ? hsplit : 0;
  const int kend = half ? (qt + 1) * 64 : hsplit;
  const int nss = (kend - kstart) >> 6;     // 64-key supersteps

  const int tid = threadIdx.x;
  const int lane = tid & 63, w = tid >> 6;
  const int cidx = lane & 15, g = lane >> 4;
  const int g8 = g * 8, g4 = g * 4;
  const int sw7 = cidx & 7;
  short* Ps = smem + 16384 + w * 1024;      // [16 q][64 k] swizzled, per wave

  const short* Qb = ws + QB_OFF + (size_t)b * SS * DQ;
  const short* Kb = ws + KB_OFF + (size_t)b * SS * DQ;
  const short* Vt = ws + VT_OFF + (size_t)b * 64 * SS;

  const int qrow = q0 + w * 16;             // wave w owns queries qrow..qrow+15
  const int qglob = qrow + cidx;            // this lane's query
  short8 qf0 = *(const short8*)&Qb[(size_t)qglob * DQ + g8];
  short8 qf1 = *(const short8*)&Qb[(size_t)qglob * DQ + 32 + g8];

  // staging: round r covers rows r*32..r*32+31; (row+32)&7 == row&7
  const int srow = tid >> 3, sgr = tid & 7;
  const int ssw = (sgr ^ (srow & 7)) * 8;
  const short* kb0 = Kb + (size_t)(kstart + srow) * DQ + ssw;
  const short* kb1 = Kb + (size_t)(kstart + srow + 32) * DQ + ssw;
  const short* vb0 = Vt + (size_t)srow * SS + kstart + ssw;
  const short* vb1 = Vt + (size_t)(srow + 32) * SS + kstart + ssw;
  const int dst0 = (w * 64) * 8, dst1 = (256 + w * 64) * 8;

  f32x4 o[4];
  #pragma unroll
  for (int i = 0; i < 4; ++i) o[i] = (f32x4){0.f, 0.f, 0.f, 0.f};
  float lsum = 0.f;

  if (nss > 0) {
    // preamble: local superstep 0 -> buffer 0
    async16(kb0, &smem[dst0]);
    async16(kb1, &smem[dst1]);
    async16(vb0, &smem[8192 + dst0]);
    async16(vb1, &smem[8192 + dst1]);

    for (int ssi = 0; ssi < nss; ++ssi) {
      __syncthreads();   // drains prefetch of ss `ssi` (issued last iteration)

      {   // prefetch ss+1 into the other buffer (clamped: always in-bounds)
        int nb = (ssi + 1) * 64;
        if (nb >= kend - kstart) nb = 0;    // dead prefetch, valid addr
        const int nbuf = ((ssi + 1) & 1) * 4096;
        const size_t koff = (size_t)nb * DQ;
        async16(kb0 + koff, &smem[nbuf + dst0]);
        async16(kb1 + koff, &smem[nbuf + dst1]);
        async16(vb0 + nb, &smem[8192 + nbuf + dst0]);
        async16(vb1 + nb, &smem[8192 + nbuf + dst1]);
      }

      const short* Kc = smem + (ssi & 1) * 4096;
      const short* Vc = smem + 8192 + (ssi & 1) * 4096;
      const int kbase = kstart + ssi * 64;

      // S^T = K Q^T : 4 key-tiles of 16
      f32x4 sc[4];
      __builtin_amdgcn_s_setprio(1);
      #pragma unroll
      for (int ct = 0; ct < 4; ++ct) {
        int krow = ct * 16 + cidx;          // krow&7 == sw7
        short8 kf0 = *(const short8*)&Kc[krow * 64 + ((g ^ sw7) * 8)];
        short8 kf1 = *(const short8*)&Kc[krow * 64 + (((g + 4) ^ sw7) * 8)];
        f32x4 a = (f32x4){0.f, 0.f, 0.f, 0.f};
        a = __builtin_amdgcn_mfma_f32_16x16x32_bf16(kf0, qf0, a, 0, 0, 0);
        a = __builtin_amdgcn_mfma_f32_16x16x32_bf16(kf1, qf1, a, 0, 0, 0);
        sc[ct] = a;
      }
      __builtin_amdgcn_s_setprio(0);
      if (ssi == nss - 1) {                 // diagonal tile: mask key > q
        #pragma unroll
        for (int ct = 0; ct < 4; ++ct) {
          int key = kbase + ct * 16 + g4;
          #pragma unroll
          for (int rr = 0; rr < 4; ++rr)
            if (key + rr > qglob) sc[ct][rr] = -1e30f;
        }
      }
      // static-max softmax: p = 2^s, per-lane lsum, no rescale
      #pragma unroll
      for (int ct = 0; ct < 4; ++ct) {
        #pragma unroll
        for (int rr = 0; rr < 4; ++rr) {
          float p = __builtin_amdgcn_exp2f(sc[ct][rr]);
          sc[ct][rr] = p;
          lsum += p;
        }
        // P^T -> Ps[q][key] (wave-local, swizzled), one b64 write per ct
        int gb = ct * 2 + (g >> 1);
        uint2 pk;
        pk.x = cvtpk(sc[ct][0], sc[ct][1]);
        pk.y = cvtpk(sc[ct][2], sc[ct][3]);
        *(uint2*)&Ps[cidx * 64 + ((gb ^ sw7) * 8) + (g & 1) * 4] = pk;
      }
      // O^T += V^T P^T  (K=64 keys -> 2 x K32 per d-tile)
      __builtin_amdgcn_s_setprio(1);
      #pragma unroll
      for (int ks = 0; ks < 2; ++ks) {
        short8 pf = *(const short8*)&Ps[cidx * 64 + (((ks * 4 + g) ^ sw7) * 8)];
        #pragma unroll
        for (int dt = 0; dt < 4; ++dt) {
          int vrow = dt * 16 + cidx;        // vrow&7 == sw7
          short8 vf = *(const short8*)&Vc[vrow * 64 + (((ks * 4 + g) ^ sw7) * 8)];
          o[dt] = __builtin_amdgcn_mfma_f32_16x16x32_bf16(vf, pf, o[dt], 0, 0, 0);
        }
      }
      __builtin_amdgcn_s_setprio(0);
    }
  }

  // query qglob's partial lsum sits in lanes {cidx, cidx+16, cidx+32, cidx+48}
  lsum += __shfl_xor(lsum, 16);
  lsum += __shfl_xor(lsum, 32);

  // unnormalized partial store; lane holds d = dt*16 + g4 + r for query qglob
  float* op = Op + (size_t)half * (M_ROWS * DQ) + ((size_t)b * SS + qglob) * DQ;
  #pragma unroll
  for (int dt = 0; dt < 4; ++dt) {
    float4 v = make_float4(o[dt][0], o[dt][1], o[dt][2], o[dt][3]);
    *(float4*)&op[dt * 16 + g4] = v;
  }
  if (g == 0)          // lanes 0..15 cover this wave's 16 queries
    Ls[(size_t)half * M_ROWS + (size_t)b * SS + qglob] = lsum;
}

// ---------------------------------------------------------------------------
// Kernel 3: combine halves + normalize.  O = (O0+O1) / (l0+l1).
// (proven code, unchanged)
// ---------------------------------------------------------------------------
__global__ __launch_bounds__(256) void norm_kernel(
    const float* __restrict__ Op, const float* __restrict__ Ls,
    float* __restrict__ O) {
  int idx = blockIdx.x * 256 + threadIdx.x;   // 0..524287
  int row = idx >> 4, q4 = idx & 15;
  float li = 1.0f / (Ls[row] + Ls[M_ROWS + row]);
  float4 a = *(const float4*)&Op[(size_t)row * DQ + q4 * 4];
  float4 c = *(const float4*)&Op[(size_t)(M_ROWS + row) * DQ + q4 * 4];
  float4 v = make_float4((a.x + c.x) * li, (a.y + c.y) * li,
                         (a.z + c.z) * li, (a.w + c.w) * li);
  *(float4*)&O[(size_t)row * DQ + q4 * 4] = v;
}

extern "C" void kernel_launch(void* const* d_in, const int* in_sizes, int n_in,
                              void* d_out, int out_size, void* d_ws, size_t ws_size,
                              hipStream_t stream) {
  const float* x  = (const float*)d_in[0];
  const float* Wq = (const float*)d_in[1];
  const float* Wk = (const float*)d_in[2];
  const float* Wv = (const float*)d_in[3];
  short* ws = (short*)d_ws;          // ~29.8 MB bf16/f32 scratch
  float* out = (float*)d_out;
  float* Op = (float*)(ws + OP_OFF);
  float* Ls = (float*)(ws + LS_OFF);

  prep_w_kernel<<<288, 256, 0, stream>>>(Wq, Wk, Wv, ws);
  qkv_proj_v3<<<M_ROWS / 64, 512, 0, stream>>>(x, ws, ws);
  flash_mfma<<<1024, 256, 0, stream>>>(ws, Op, Ls);
  norm_kernel<<<2048, 256, 0, stream>>>(Op, Ls, out);
}

// Round 8
// 122.975 us; speedup vs baseline: 1.3625x; 1.0448x over previous
//
#include <hip/hip_runtime.h>
#include <hip/hip_bf16.h>
#include <math.h>

#define BB 16
#define SS 2048
#define DM 384
#define DQ 64
#define M_ROWS (BB * SS)   // 32768

typedef short short8 __attribute__((ext_vector_type(8)));
typedef float f32x4  __attribute__((ext_vector_type(4)));
typedef unsigned u32x4 __attribute__((ext_vector_type(4)));

// ws layout (shorts): Wt [192][384] | Qb [B][S][64] | Kb [B][S][64] | Vt [B][64][S]
//                     | Op [2][B*S][64] f32 | Ls [2][B*S] f32
#define WT_OFF 0
#define QB_OFF 73728
#define KB_OFF (QB_OFF + M_ROWS * DQ)
#define VT_OFF (KB_OFF + M_ROWS * DQ)
#define OP_OFF (VT_OFF + BB * DQ * SS)          // 16B aligned
#define LS_OFF (OP_OFF + 2 * M_ROWS * DQ * 2)   // Op = 2*32768*64 f32

#define QSCALE 0.18033688011112042f   // 0.125 * log2(e); softmax in exp2

__device__ __forceinline__ short f2bf(float f) {
  unsigned u = __builtin_bit_cast(unsigned, f);
  unsigned r = (u + 0x7fffu + ((u >> 16) & 1u)) >> 16;
  return (short)r;
}
// packed RNE f32x2 -> bf16x2 (1 VALU op per 2 values)
__device__ __forceinline__ unsigned cvtpk(float a, float b) {
  unsigned r;
  asm("v_cvt_pk_bf16_f32 %0, %1, %2" : "=v"(r) : "v"(a), "v"(b));
  return r;
}
__device__ __forceinline__ void async16(const short* g, short* l) {
  __builtin_amdgcn_global_load_lds(
      (const __attribute__((address_space(1))) unsigned int*)g,
      (__attribute__((address_space(3))) unsigned int*)l, 16, 0, 0);
}

// ---------------------------------------------------------------------------
// Kernel 0: W [384,64] fp32 x3 -> Wt rows [mat*64+n][384] bf16.  288 x 256.
// (proven R4 code)
// ---------------------------------------------------------------------------
__global__ void prep_w_kernel(const float* __restrict__ Wq,
                              const float* __restrict__ Wk,
                              const float* __restrict__ Wv,
                              short* __restrict__ ws) {
  int o = blockIdx.x * 256 + threadIdx.x;        // 0 .. 73727
  int mat = o / (DM * DQ);
  int r = o % (DM * DQ);
  int k = r / DQ, n = r % DQ;                    // coalesced read
  const float* W = (mat == 0) ? Wq : (mat == 1) ? Wk : Wv;
  ws[WT_OFF + mat * (DM * DQ) + n * DM + k] = f2bf(W[k * DQ + n]);
}

// ---------------------------------------------------------------------------
// Kernel 1: QKV projection, bf16 MFMA 16x16x32.  (proven R4 v1 code --
// v2 per-matrix blocks regressed +6.7 us (3x x reads), v3 8-wave regressed
// +4.9 us (occupancy was not the constraint).  v1 is the best measured.)
// Block: 64 rows x 192 cols, 256 thr = 4 waves x 16 rows.  grid 512.
// Double-buffered Wtc staging, one barrier per K-iter, Ep overlays dbuf.
// ---------------------------------------------------------------------------
__global__ __launch_bounds__(256) void qkv_proj_mfma(
    const float* __restrict__ x, const short* __restrict__ ws_r,
    short* __restrict__ ws_w) {
  __shared__ short smem[2 * 192 * 64];   // Wtc dbuf (2 x 24 KB); Ep aliases
  short* Ep = smem;                      // 64*200 shorts, post-loop only
  const int tid = threadIdx.x;
  const int lane = tid & 63, w = tid >> 6;
  const int cidx = lane & 15, g = lane >> 4;
  const int g8 = g * 8, g4 = g * 4;
  const int sw7 = cidx & 7;
  const int rows0 = blockIdx.x * 64;
  const short* Wt = ws_r + WT_OFF;

  f32x4 acc[12];
  #pragma unroll
  for (int i = 0; i < 12; ++i) acc[i] = (f32x4){0.f, 0.f, 0.f, 0.f};

  const float* xr = x + (size_t)(rows0 + 16 * w + cidx) * DM;

  // prologue: stage k-iter 0 into buf0, preload x regs for iter 0
  #pragma unroll
  for (int it = 0; it < 6; ++it) {
    int i = it * 256 + tid;
    int row = i >> 3, gr = i & 7;
    const short* src = Wt + row * DM + ((gr ^ (row & 7)) * 8);
    async16(src, &smem[(it * 256 + w * 64) * 8]);
  }
  float4 xc0 = *(const float4*)(xr + g8);
  float4 xc1 = *(const float4*)(xr + g8 + 4);
  float4 xc2 = *(const float4*)(xr + 32 + g8);
  float4 xc3 = *(const float4*)(xr + 32 + g8 + 4);

  for (int ki = 0; ki < 6; ++ki) {
    __syncthreads();   // drains stage(ki) + this iter's x loads
    const short* cur = smem + (ki & 1) * 12288;

    if (ki < 5) {      // prefetch stage(ki+1) into the other buffer
      short* nxt = smem + ((ki + 1) & 1) * 12288;
      const int kn = (ki + 1) * 64;
      #pragma unroll
      for (int it = 0; it < 6; ++it) {
        int i = it * 256 + tid;
        int row = i >> 3, gr = i & 7;
        const short* src = Wt + row * DM + kn + ((gr ^ (row & 7)) * 8);
        async16(src, &nxt[(it * 256 + w * 64) * 8]);
      }
    }

    u32x4 ua, ub;
    ua[0] = cvtpk(xc0.x, xc0.y); ua[1] = cvtpk(xc0.z, xc0.w);
    ua[2] = cvtpk(xc1.x, xc1.y); ua[3] = cvtpk(xc1.z, xc1.w);
    ub[0] = cvtpk(xc2.x, xc2.y); ub[1] = cvtpk(xc2.z, xc2.w);
    ub[2] = cvtpk(xc3.x, xc3.y); ub[3] = cvtpk(xc3.z, xc3.w);
    short8 a0 = __builtin_bit_cast(short8, ua);
    short8 a1 = __builtin_bit_cast(short8, ub);

    if (ki < 5) {      // preload next iter's x (in flight during MFMA)
      const float* xn = xr + (ki + 1) * 64;
      xc0 = *(const float4*)(xn + g8);
      xc1 = *(const float4*)(xn + g8 + 4);
      xc2 = *(const float4*)(xn + 32 + g8);
      xc3 = *(const float4*)(xn + 32 + g8 + 4);
    }

    #pragma unroll
    for (int ct = 0; ct < 12; ++ct) {
      int row = ct * 16 + cidx;
      short8 b0 = *(const short8*)&cur[row * 64 + ((g ^ sw7) * 8)];
      short8 b1 = *(const short8*)&cur[row * 64 + (((g + 4) ^ sw7) * 8)];
      acc[ct] = __builtin_amdgcn_mfma_f32_16x16x32_bf16(a0, b0, acc[ct], 0, 0, 0);
      acc[ct] = __builtin_amdgcn_mfma_f32_16x16x32_bf16(a1, b1, acc[ct], 0, 0, 0);
    }
  }

  __syncthreads();     // all compute done; safe to clobber dbuf with Ep
  const int erow = 16 * w + g4;
  #pragma unroll
  for (int ct = 0; ct < 4; ++ct) {
    unsigned q01 = cvtpk(acc[ct][0] * QSCALE, acc[ct][1] * QSCALE);
    unsigned q23 = cvtpk(acc[ct][2] * QSCALE, acc[ct][3] * QSCALE);
    unsigned k01 = cvtpk(acc[4 + ct][0], acc[4 + ct][1]);
    unsigned k23 = cvtpk(acc[4 + ct][2], acc[4 + ct][3]);
    unsigned v01 = cvtpk(acc[8 + ct][0], acc[8 + ct][1]);
    unsigned v23 = cvtpk(acc[8 + ct][2], acc[8 + ct][3]);
    Ep[(erow + 0) * 200 + ct * 16 + cidx] = (short)q01;
    Ep[(erow + 1) * 200 + ct * 16 + cidx] = (short)(q01 >> 16);
    Ep[(erow + 2) * 200 + ct * 16 + cidx] = (short)q23;
    Ep[(erow + 3) * 200 + ct * 16 + cidx] = (short)(q23 >> 16);
    Ep[(erow + 0) * 200 + 64 + ct * 16 + cidx] = (short)k01;
    Ep[(erow + 1) * 200 + 64 + ct * 16 + cidx] = (short)(k01 >> 16);
    Ep[(erow + 2) * 200 + 64 + ct * 16 + cidx] = (short)k23;
    Ep[(erow + 3) * 200 + 64 + ct * 16 + cidx] = (short)(k23 >> 16);
    Ep[(ct * 16 + cidx) * 200 + 128 + erow + 0] = (short)v01;
    Ep[(ct * 16 + cidx) * 200 + 128 + erow + 1] = (short)(v01 >> 16);
    Ep[(ct * 16 + cidx) * 200 + 128 + erow + 2] = (short)v23;
    Ep[(ct * 16 + cidx) * 200 + 128 + erow + 3] = (short)(v23 >> 16);
  }
  __syncthreads();

  short* Qb = ws_w + QB_OFF;
  short* Kb = ws_w + KB_OFF;
  short* Vt = ws_w + VT_OFF;
  const int bidx = rows0 >> 11;
  const int srow0 = rows0 & 2047;
  #pragma unroll
  for (int t2 = 0; t2 < 2; ++t2) {
    int i = t2 * 256 + tid;            // 0..511
    int row = i >> 3, gq = i & 7;
    *(short8*)&Qb[(size_t)(rows0 + row) * DQ + gq * 8] =
        *(const short8*)&Ep[row * 200 + gq * 8];
    *(short8*)&Kb[(size_t)(rows0 + row) * DQ + gq * 8] =
        *(const short8*)&Ep[row * 200 + 64 + gq * 8];
    *(short8*)&Vt[(size_t)bidx * (64 * SS) + (size_t)row * SS + srow0 + gq * 8] =
        *(const short8*)&Ep[row * 200 + 128 + gq * 8];   // row = d here
  }
}

// ---------------------------------------------------------------------------
// Kernel 2: causal flash attention, KEY-SPLIT 2x, LDS-staged.
// (proven R4 code: 1024 blocks -> 4 blocks/CU, flat 33 half-ss/CU balance;
// barrier-free variant regressed to 65.7 us -- LDS staging is required.)
// ---------------------------------------------------------------------------
__global__ __launch_bounds__(256, 4) void flash_mfma(
    const short* __restrict__ ws, float* __restrict__ Op,
    float* __restrict__ Ls) {
  __shared__ short smem[20480];   // KsA 0 | KsB 4096 | VtsA 8192 | VtsB 12288 | Ps 16384
  const int l = blockIdx.x;                 // 0..1023
  const int b = l & 15;
  const int r = l >> 4;                     // 0..63
  const int qtp = r & 31;
  const int half = r >> 5;                  // 0 or 1
  const int qt = (qtp < 16) ? qtp : 47 - qtp;   // causal balance pairing
  const int q0 = qt * 64;
  const int hsplit = ((qt + 2) >> 1) * 64;  // ceil((qt+1)/2)*64
  const int kstart = half ? hsplit : 0;
  const int kend = half ? (qt + 1) * 64 : hsplit;
  const int nss = (kend - kstart) >> 6;     // 64-key supersteps

  const int tid = threadIdx.x;
  const int lane = tid & 63, w = tid >> 6;
  const int cidx = lane & 15, g = lane >> 4;
  const int g8 = g * 8, g4 = g * 4;
  const int sw7 = cidx & 7;
  short* Ps = smem + 16384 + w * 1024;      // [16 q][64 k] swizzled, per wave

  const short* Qb = ws + QB_OFF + (size_t)b * SS * DQ;
  const short* Kb = ws + KB_OFF + (size_t)b * SS * DQ;
  const short* Vt = ws + VT_OFF + (size_t)b * 64 * SS;

  const int qrow = q0 + w * 16;             // wave w owns queries qrow..qrow+15
  const int qglob = qrow + cidx;            // this lane's query
  short8 qf0 = *(const short8*)&Qb[(size_t)qglob * DQ + g8];
  short8 qf1 = *(const short8*)&Qb[(size_t)qglob * DQ + 32 + g8];

  // staging: round r covers rows r*32..r*32+31; (row+32)&7 == row&7
  const int srow = tid >> 3, sgr = tid & 7;
  const int ssw = (sgr ^ (srow & 7)) * 8;
  const short* kb0 = Kb + (size_t)(kstart + srow) * DQ + ssw;
  const short* kb1 = Kb + (size_t)(kstart + srow + 32) * DQ + ssw;
  const short* vb0 = Vt + (size_t)srow * SS + kstart + ssw;
  const short* vb1 = Vt + (size_t)(srow + 32) * SS + kstart + ssw;
  const int dst0 = (w * 64) * 8, dst1 = (256 + w * 64) * 8;

  f32x4 o[4];
  #pragma unroll
  for (int i = 0; i < 4; ++i) o[i] = (f32x4){0.f, 0.f, 0.f, 0.f};
  float lsum = 0.f;

  if (nss > 0) {
    // preamble: local superstep 0 -> buffer 0
    async16(kb0, &smem[dst0]);
    async16(kb1, &smem[dst1]);
    async16(vb0, &smem[8192 + dst0]);
    async16(vb1, &smem[8192 + dst1]);

    for (int ssi = 0; ssi < nss; ++ssi) {
      __syncthreads();   // drains prefetch of ss `ssi` (issued last iteration)

      {   // prefetch ss+1 into the other buffer (clamped: always in-bounds)
        int nb = (ssi + 1) * 64;
        if (nb >= kend - kstart) nb = 0;    // dead prefetch, valid addr
        const int nbuf = ((ssi + 1) & 1) * 4096;
        const size_t koff = (size_t)nb * DQ;
        async16(kb0 + koff, &smem[nbuf + dst0]);
        async16(kb1 + koff, &smem[nbuf + dst1]);
        async16(vb0 + nb, &smem[8192 + nbuf + dst0]);
        async16(vb1 + nb, &smem[8192 + nbuf + dst1]);
      }

      const short* Kc = smem + (ssi & 1) * 4096;
      const short* Vc = smem + 8192 + (ssi & 1) * 4096;
      const int kbase = kstart + ssi * 64;

      // S^T = K Q^T : 4 key-tiles of 16
      f32x4 sc[4];
      __builtin_amdgcn_s_setprio(1);
      #pragma unroll
      for (int ct = 0; ct < 4; ++ct) {
        int krow = ct * 16 + cidx;          // krow&7 == sw7
        short8 kf0 = *(const short8*)&Kc[krow * 64 + ((g ^ sw7) * 8)];
        short8 kf1 = *(const short8*)&Kc[krow * 64 + (((g + 4) ^ sw7) * 8)];
        f32x4 a = (f32x4){0.f, 0.f, 0.f, 0.f};
        a = __builtin_amdgcn_mfma_f32_16x16x32_bf16(kf0, qf0, a, 0, 0, 0);
        a = __builtin_amdgcn_mfma_f32_16x16x32_bf16(kf1, qf1, a, 0, 0, 0);
        sc[ct] = a;
      }
      __builtin_amdgcn_s_setprio(0);
      if (ssi == nss - 1) {                 // diagonal tile: mask key > q
        #pragma unroll
        for (int ct = 0; ct < 4; ++ct) {
          int key = kbase + ct * 16 + g4;
          #pragma unroll
          for (int rr = 0; rr < 4; ++rr)
            if (key + rr > qglob) sc[ct][rr] = -1e30f;
        }
      }
      // static-max softmax: p = 2^s, per-lane lsum, no rescale
      #pragma unroll
      for (int ct = 0; ct < 4; ++ct) {
        #pragma unroll
        for (int rr = 0; rr < 4; ++rr) {
          float p = __builtin_amdgcn_exp2f(sc[ct][rr]);
          sc[ct][rr] = p;
          lsum += p;
        }
        // P^T -> Ps[q][key] (wave-local, swizzled), one b64 write per ct
        int gb = ct * 2 + (g >> 1);
        uint2 pk;
        pk.x = cvtpk(sc[ct][0], sc[ct][1]);
        pk.y = cvtpk(sc[ct][2], sc[ct][3]);
        *(uint2*)&Ps[cidx * 64 + ((gb ^ sw7) * 8) + (g & 1) * 4] = pk;
      }
      // O^T += V^T P^T  (K=64 keys -> 2 x K32 per d-tile)
      __builtin_amdgcn_s_setprio(1);
      #pragma unroll
      for (int ks = 0; ks < 2; ++ks) {
        short8 pf = *(const short8*)&Ps[cidx * 64 + (((ks * 4 + g) ^ sw7) * 8)];
        #pragma unroll
        for (int dt = 0; dt < 4; ++dt) {
          int vrow = dt * 16 + cidx;        // vrow&7 == sw7
          short8 vf = *(const short8*)&Vc[vrow * 64 + (((ks * 4 + g) ^ sw7) * 8)];
          o[dt] = __builtin_amdgcn_mfma_f32_16x16x32_bf16(vf, pf, o[dt], 0, 0, 0);
        }
      }
      __builtin_amdgcn_s_setprio(0);
    }
  }

  // query qglob's partial lsum sits in lanes {cidx, cidx+16, cidx+32, cidx+48}
  lsum += __shfl_xor(lsum, 16);
  lsum += __shfl_xor(lsum, 32);

  // unnormalized partial store; lane holds d = dt*16 + g4 + r for query qglob
  float* op = Op + (size_t)half * (M_ROWS * DQ) + ((size_t)b * SS + qglob) * DQ;
  #pragma unroll
  for (int dt = 0; dt < 4; ++dt) {
    float4 v = make_float4(o[dt][0], o[dt][1], o[dt][2], o[dt][3]);
    *(float4*)&op[dt * 16 + g4] = v;
  }
  if (g == 0)          // lanes 0..15 cover this wave's 16 queries
    Ls[(size_t)half * M_ROWS + (size_t)b * SS + qglob] = lsum;
}

// ---------------------------------------------------------------------------
// Kernel 3: combine halves + normalize.  O = (O0+O1) / (l0+l1).
// (proven R4 code)
// ---------------------------------------------------------------------------
__global__ __launch_bounds__(256) void norm_kernel(
    const float* __restrict__ Op, const float* __restrict__ Ls,
    float* __restrict__ O) {
  int idx = blockIdx.x * 256 + threadIdx.x;   // 0..524287
  int row = idx >> 4, q4 = idx & 15;
  float li = 1.0f / (Ls[row] + Ls[M_ROWS + row]);
  float4 a = *(const float4*)&Op[(size_t)row * DQ + q4 * 4];
  float4 c = *(const float4*)&Op[(size_t)(M_ROWS + row) * DQ + q4 * 4];
  float4 v = make_float4((a.x + c.x) * li, (a.y + c.y) * li,
                         (a.z + c.z) * li, (a.w + c.w) * li);
  *(float4*)&O[(size_t)row * DQ + q4 * 4] = v;
}

extern "C" void kernel_launch(void* const* d_in, const int* in_sizes, int n_in,
                              void* d_out, int out_size, void* d_ws, size_t ws_size,
                              hipStream_t stream) {
  const float* x  = (const float*)d_in[0];
  const float* Wq = (const float*)d_in[1];
  const float* Wk = (const float*)d_in[2];
  const float* Wv = (const float*)d_in[3];
  short* ws = (short*)d_ws;          // ~29.8 MB bf16/f32 scratch
  float* out = (float*)d_out;
  float* Op = (float*)(ws + OP_OFF);
  float* Ls = (float*)(ws + LS_OFF);

  prep_w_kernel<<<288, 256, 0, stream>>>(Wq, Wk, Wv, ws);
  qkv_proj_mfma<<<M_ROWS / 64, 256, 0, stream>>>(x, ws, ws);
  flash_mfma<<<1024, 256, 0, stream>>>(ws, Op, Ls);
  norm_kernel<<<2048, 256, 0, stream>>>(Op, Ls, out);
}